// Round 5
// baseline (194.170 us; speedup 1.0000x reference)
//
#include <hip/hip_runtime.h>

// RBF Gram, symmetric-aware: out[i,j] = exp(-0.5*||xi-xj||^2), x:[8192][64] fp32.
// Lower-triangle 128x128 blocks only (2080 of 4096); each block stores its tile
// and the transposed mirror. Zero LDS: operands stream from L2-resident x via
// dwordx4; 8x8 register blocking (1.0 -> no LDS bytes at all per FMA).

#define GAMMA 0.5f

__global__ __launch_bounds__(256) void rbf_sym(const float* __restrict__ x,
                                               float* __restrict__ out, int N) {
    // linear bid -> lower-triangle (bi >= bj), bid = bi*(bi+1)/2 + bj
    int bid = blockIdx.x;
    int bi = (int)((sqrtf(8.0f * (float)bid + 1.0f) - 1.0f) * 0.5f);
    while ((bi + 1) * (bi + 2) / 2 <= bid) ++bi;
    while (bi * (bi + 1) / 2 > bid) --bi;
    int bj = bid - bi * (bi + 1) / 2;

    const int tid = threadIdx.x;
    const int tx = tid & 15, ty = tid >> 4;
    const int i0 = bi * 128 + ty * 8;   // 8 rows owned by this thread
    const int j0 = bj * 128 + tx * 8;   // 8 cols owned by this thread

    const float* xa = x + (size_t)i0 * 64;
    const float* xb = x + (size_t)j0 * 64;

    float acc[8][8] = {};
    float sqa[8] = {}, sqb[8] = {};

    #pragma unroll 1
    for (int k0 = 0; k0 < 64; k0 += 4) {
        float4 a[8], b[8];
        #pragma unroll
        for (int m = 0; m < 8; ++m) a[m] = *(const float4*)(xa + m * 64 + k0);
        #pragma unroll
        for (int n = 0; n < 8; ++n) b[n] = *(const float4*)(xb + n * 64 + k0);
        #pragma unroll
        for (int m = 0; m < 8; ++m) {
            sqa[m] = fmaf(a[m].x, a[m].x, sqa[m]);
            sqa[m] = fmaf(a[m].y, a[m].y, sqa[m]);
            sqa[m] = fmaf(a[m].z, a[m].z, sqa[m]);
            sqa[m] = fmaf(a[m].w, a[m].w, sqa[m]);
            sqb[m] = fmaf(b[m].x, b[m].x, sqb[m]);
            sqb[m] = fmaf(b[m].y, b[m].y, sqb[m]);
            sqb[m] = fmaf(b[m].z, b[m].z, sqb[m]);
            sqb[m] = fmaf(b[m].w, b[m].w, sqb[m]);
        }
        #pragma unroll
        for (int m = 0; m < 8; ++m)
            #pragma unroll
            for (int n = 0; n < 8; ++n) {
                acc[m][n] = fmaf(a[m].x, b[n].x, acc[m][n]);
                acc[m][n] = fmaf(a[m].y, b[n].y, acc[m][n]);
                acc[m][n] = fmaf(a[m].z, b[n].z, acc[m][n]);
                acc[m][n] = fmaf(a[m].w, b[n].w, acc[m][n]);
            }
    }

    // epilogue: exp computed ONCE per symmetric pair
    #pragma unroll
    for (int m = 0; m < 8; ++m)
        #pragma unroll
        for (int n = 0; n < 8; ++n) {
            float d2 = sqa[m] + sqb[n] - 2.0f * acc[m][n];
            d2 = fmaxf(d2, 0.0f);
            acc[m][n] = __expf(-GAMMA * d2);
        }

    // normal tile store (coalesced: tx-contiguous 512B runs)
    #pragma unroll
    for (int m = 0; m < 8; ++m) {
        float4 r0 = {acc[m][0], acc[m][1], acc[m][2], acc[m][3]};
        float4 r1 = {acc[m][4], acc[m][5], acc[m][6], acc[m][7]};
        float* p = out + (size_t)(i0 + m) * N + j0;
        *(float4*)p = r0;
        *(float4*)(p + 4) = r1;
    }
    // mirror tile store (transposed; L2 merges the 16B-granular pattern)
    if (bi != bj) {
        #pragma unroll
        for (int n = 0; n < 8; ++n) {
            float4 c0 = {acc[0][n], acc[1][n], acc[2][n], acc[3][n]};
            float4 c1 = {acc[4][n], acc[5][n], acc[6][n], acc[7][n]};
            float* p = out + (size_t)(j0 + n) * N + i0;
            *(float4*)p = c0;
            *(float4*)(p + 4) = c1;
        }
    }
}

extern "C" void kernel_launch(void* const* d_in, const int* in_sizes, int n_in,
                              void* d_out, int out_size, void* d_ws, size_t ws_size,
                              hipStream_t stream) {
    (void)n_in; (void)d_ws; (void)ws_size; (void)out_size;
    const float* x = (const float*)d_in[0];
    float* out = (float*)d_out;
    const int K = 64;
    const int N = in_sizes[0] / K;        // 8192
    const int nb = N / 128;               // 64 row-blocks
    const int grid = nb * (nb + 1) / 2;   // 2080 lower-triangle blocks
    rbf_sym<<<grid, dim3(256), 0, stream>>>(x, out, N);
}

// Round 6
// 87.065 us; speedup vs baseline: 2.2302x; 2.2302x over previous
//
#include <hip/hip_runtime.h>

// RBF Gram via bf16-split MFMA: out[i,j] = exp(-0.5*||xi-xj||^2), x:[8192][64] fp32.
// dot(xi,xj) on matrix cores: x = hi + lo (bf16 each), dot = hh + hl + lh (lo*lo
// dropped, ~2e-4). sq norms in fp32. Write-floor-bound (268 MB out), so no
// symmetry tricks — full 64x64 grid of 128x128 tiles, 4 waves/block.

#define GAMMA 0.5f
#define LDR 72  // LDS row stride in bf16 elems: 144 B -> 16B-aligned b128 frags, balanced banks

typedef __attribute__((ext_vector_type(8))) short short8;
typedef __attribute__((ext_vector_type(4))) float f32x4;

__device__ __forceinline__ unsigned short bf16_rne(float f) {
    unsigned int u = __builtin_bit_cast(unsigned int, f);
    u += 0x7fffu + ((u >> 16) & 1u);
    return (unsigned short)(u >> 16);
}

__device__ __forceinline__ void split4(float4 v, uint2& hw, uint2& lw, float& s) {
    float e[4] = {v.x, v.y, v.z, v.w};
    unsigned short h[4], l[4];
    s = 0.f;
    #pragma unroll
    for (int i = 0; i < 4; ++i) {
        h[i] = bf16_rne(e[i]);
        float hf = __builtin_bit_cast(float, (unsigned int)h[i] << 16);
        l[i] = bf16_rne(e[i] - hf);
        s = fmaf(e[i], e[i], s);
    }
    hw.x = (unsigned)h[0] | ((unsigned)h[1] << 16);
    hw.y = (unsigned)h[2] | ((unsigned)h[3] << 16);
    lw.x = (unsigned)l[0] | ((unsigned)l[1] << 16);
    lw.y = (unsigned)l[2] | ((unsigned)l[3] << 16);
}

__global__ __launch_bounds__(256) void rbf_mfma(const float* __restrict__ x,
                                                float* __restrict__ out, int N) {
    __shared__ unsigned short Ah[128 * LDR], Al[128 * LDR];
    __shared__ unsigned short Bh[128 * LDR], Bl[128 * LDR];
    __shared__ float sqA[128], sqB[128];

    const int tid = threadIdx.x;
    const int i0 = blockIdx.y * 128;
    const int j0 = blockIdx.x * 128;

    // ---- stage: fp32 -> bf16 hi/lo into LDS (coalesced loads), sq-norms via 16-lane reduce
    const float4* a4 = (const float4*)(x + (size_t)i0 * 64);
    const float4* b4 = (const float4*)(x + (size_t)j0 * 64);
    #pragma unroll
    for (int it = 0; it < 8; ++it) {
        int q = it * 256 + tid;          // float4 index in 128x16 tile
        int row = q >> 4, c4 = q & 15;
        uint2 hw, lw; float s;
        split4(a4[q], hw, lw, s);
        *(uint2*)&Ah[row * LDR + c4 * 4] = hw;
        *(uint2*)&Al[row * LDR + c4 * 4] = lw;
        s += __shfl_xor(s, 1); s += __shfl_xor(s, 2);
        s += __shfl_xor(s, 4); s += __shfl_xor(s, 8);
        if (c4 == 0) sqA[row] = s;
        split4(b4[q], hw, lw, s);
        *(uint2*)&Bh[row * LDR + c4 * 4] = hw;
        *(uint2*)&Bl[row * LDR + c4 * 4] = lw;
        s += __shfl_xor(s, 1); s += __shfl_xor(s, 2);
        s += __shfl_xor(s, 4); s += __shfl_xor(s, 8);
        if (c4 == 0) sqB[row] = s;
    }
    __syncthreads();

    // ---- MFMA: wave quadrant 64x64 = 4x4 frags of 16x16, K=64 = 2 ksteps x 3 passes
    const int w = tid >> 6, lane = tid & 63;
    const int wr = (w >> 1) * 64, wc = (w & 1) * 64;
    const int fr = lane & 15, kg = lane >> 4;

    f32x4 acc[4][4];
    #pragma unroll
    for (int m = 0; m < 4; ++m)
        #pragma unroll
        for (int n = 0; n < 4; ++n) acc[m][n] = (f32x4)(0.f);

    #pragma unroll
    for (int ks = 0; ks < 2; ++ks) {
        const int k = ks * 32 + kg * 8;
        short8 ah[4], al[4], bh[4], bl[4];
        #pragma unroll
        for (int m = 0; m < 4; ++m) {
            ah[m] = *(const short8*)&Ah[(wr + m * 16 + fr) * LDR + k];
            al[m] = *(const short8*)&Al[(wr + m * 16 + fr) * LDR + k];
        }
        #pragma unroll
        for (int n = 0; n < 4; ++n) {
            bh[n] = *(const short8*)&Bh[(wc + n * 16 + fr) * LDR + k];
            bl[n] = *(const short8*)&Bl[(wc + n * 16 + fr) * LDR + k];
        }
        #pragma unroll
        for (int m = 0; m < 4; ++m)
            #pragma unroll
            for (int n = 0; n < 4; ++n)
                acc[m][n] = __builtin_amdgcn_mfma_f32_16x16x32_bf16(ah[m], bh[n], acc[m][n], 0, 0, 0);
        #pragma unroll
        for (int m = 0; m < 4; ++m)
            #pragma unroll
            for (int n = 0; n < 4; ++n)
                acc[m][n] = __builtin_amdgcn_mfma_f32_16x16x32_bf16(ah[m], bl[n], acc[m][n], 0, 0, 0);
        #pragma unroll
        for (int m = 0; m < 4; ++m)
            #pragma unroll
            for (int n = 0; n < 4; ++n)
                acc[m][n] = __builtin_amdgcn_mfma_f32_16x16x32_bf16(al[m], bh[n], acc[m][n], 0, 0, 0);
    }

    // ---- epilogue: d2 -> exp -> coalesced stores (4x64B segments per wave-instr)
    #pragma unroll
    for (int m = 0; m < 4; ++m) {
        #pragma unroll
        for (int j = 0; j < 4; ++j) {
            int ri = wr + m * 16 + kg * 4 + j;        // C/D layout: row=(lane>>4)*4+reg
            float sa = sqA[ri];
            float* po = out + (size_t)(i0 + ri) * N + j0;
            #pragma unroll
            for (int n = 0; n < 4; ++n) {
                int cj = wc + n * 16 + fr;            // col = lane&15
                float d2 = fmaf(-2.f, acc[m][n][j], sa + sqB[cj]);
                d2 = fmaxf(d2, 0.f);
                po[cj] = __expf(-GAMMA * d2);
            }
        }
    }
}

extern "C" void kernel_launch(void* const* d_in, const int* in_sizes, int n_in,
                              void* d_out, int out_size, void* d_ws, size_t ws_size,
                              hipStream_t stream) {
    (void)n_in; (void)d_ws; (void)ws_size; (void)out_size;
    const float* x = (const float*)d_in[0];
    float* out = (float*)d_out;
    const int K = 64;
    const int N = in_sizes[0] / K;   // 8192
    dim3 grid(N / 128, N / 128);
    rbf_mfma<<<grid, dim3(256), 0, stream>>>(x, out, N);
}

// Round 7
// 65.856 us; speedup vs baseline: 2.9484x; 1.3221x over previous
//
#include <hip/hip_runtime.h>

// RBF Gram via bf16-split MFMA, two-phase:
//   P1: x (fp32 [N][64]) -> Xh,Xl (bf16, XOR-swizzled per 128-row chunk) + sq[N] in d_ws
//   P2: 128x128 tiles, dot = Ah*Bh^T + Ah*Bl^T + Al*Bh^T on matrix cores (lo*lo dropped),
//       swapped-operand MFMA (computes D^T) so each lane owns 4 consecutive out columns
//       -> dwordx4 stores. out[i,j] = exp(-0.5*(sq_i+sq_j-2dot)).

#define GAMMA 0.5f

typedef __attribute__((ext_vector_type(8))) short short8;
typedef __attribute__((ext_vector_type(4))) float f32x4;

__device__ __forceinline__ unsigned short bf16_rne(float f) {
    unsigned u = __builtin_bit_cast(unsigned, f);
    u += 0x7fffu + ((u >> 16) & 1u);
    return (unsigned short)(u >> 16);
}

// ---------------- Phase 1: split + swizzle + norms ----------------
__global__ __launch_bounds__(256) void split_kernel(const float* __restrict__ x,
                                                    unsigned short* __restrict__ Xh,
                                                    unsigned short* __restrict__ Xl,
                                                    float* __restrict__ sq) {
    int tid = blockIdx.x * 256 + threadIdx.x;   // one float4 (4 elems of one row)
    int row = tid >> 4, c4 = tid & 15;
    float4 v = ((const float4*)x)[tid];
    float e[4] = {v.x, v.y, v.z, v.w};
    unsigned short h[4], l[4];
    float s = 0.f;
    #pragma unroll
    for (int i = 0; i < 4; ++i) {
        h[i] = bf16_rne(e[i]);
        float hf = __builtin_bit_cast(float, (unsigned)h[i] << 16);
        l[i] = bf16_rne(e[i] - hf);
        s = fmaf(e[i], e[i], s);
    }
    // byte offset within the 16KB 128-row chunk, XOR-swizzled (bits 4..6 by row&7)
    int rr = row & 127;
    size_t base = (size_t)(row >> 7) * 16384;
    int b = (rr * 128 + c4 * 8) ^ ((rr & 7) << 4);
    uint2 hw = {(unsigned)h[0] | ((unsigned)h[1] << 16), (unsigned)h[2] | ((unsigned)h[3] << 16)};
    uint2 lw = {(unsigned)l[0] | ((unsigned)l[1] << 16), (unsigned)l[2] | ((unsigned)l[3] << 16)};
    *(uint2*)((char*)Xh + base + b) = hw;
    *(uint2*)((char*)Xl + base + b) = lw;
    s += __shfl_xor(s, 1); s += __shfl_xor(s, 2);
    s += __shfl_xor(s, 4); s += __shfl_xor(s, 8);
    if (c4 == 0) sq[row] = s;
}

// ---------------- Phase 2: tiled MFMA GEMM + exp epilogue ----------------
__global__ __launch_bounds__(256) void rbf_mfma2(const unsigned short* __restrict__ Xh,
                                                 const unsigned short* __restrict__ Xl,
                                                 const float* __restrict__ sq,
                                                 float* __restrict__ out, int N) {
    // 4 x 16KB swizzled tiles = exactly 64 KB
    __shared__ unsigned short Ah[8192], Al[8192], Bh[8192], Bl[8192];

    const int tid = threadIdx.x;
    const int i0 = blockIdx.y * 128, j0 = blockIdx.x * 128;
    const int w = tid >> 6, lane = tid & 63;
    const int fr = lane & 15, kg = lane >> 4;
    const int wr = (w >> 1) * 64, wc = (w & 1) * 64;   // wave quadrant of 128x128

    // ---- stage: linear 64KB copy (swizzle already baked into global layout) ----
    {
        uint4* l4[4] = {(uint4*)Ah, (uint4*)Al, (uint4*)Bh, (uint4*)Bl};
        const uint4* g4[4] = {(const uint4*)(Xh + (size_t)i0 * 64),
                              (const uint4*)(Xl + (size_t)i0 * 64),
                              (const uint4*)(Xh + (size_t)j0 * 64),
                              (const uint4*)(Xl + (size_t)j0 * 64)};
        #pragma unroll
        for (int b = 0; b < 4; ++b)
            #pragma unroll
            for (int t = 0; t < 4; ++t)
                l4[b][t * 256 + tid] = g4[b][t * 256 + tid];
    }
    __syncthreads();

    // ---- K-loop: 2 ksteps x 3 passes (hh, hl, lh), swapped operands -> D^T ----
    f32x4 acc[4][4];
    #pragma unroll
    for (int p = 0; p < 4; ++p)
        #pragma unroll
        for (int q = 0; q < 4; ++q) acc[p][q] = (f32x4)(0.f);

    #pragma unroll
    for (int ks = 0; ks < 2; ++ks) {
        const int kb = ks * 64 + kg * 16;   // byte offset of this lane's 16B k-slice
        short8 ah[4], al[4], bh[4], bl[4];
        #pragma unroll
        for (int p = 0; p < 4; ++p) {
            int R = wr + p * 16 + fr;
            int off = (R * 128 + kb) ^ ((R & 7) << 4);
            ah[p] = *(const short8*)((const char*)Ah + off);
            al[p] = *(const short8*)((const char*)Al + off);
        }
        #pragma unroll
        for (int q = 0; q < 4; ++q) {
            int R = wc + q * 16 + fr;
            int off = (R * 128 + kb) ^ ((R & 7) << 4);
            bh[q] = *(const short8*)((const char*)Bh + off);
            bl[q] = *(const short8*)((const char*)Bl + off);
        }
        #pragma unroll
        for (int p = 0; p < 4; ++p)
            #pragma unroll
            for (int q = 0; q < 4; ++q)
                acc[p][q] = __builtin_amdgcn_mfma_f32_16x16x32_bf16(bh[q], ah[p], acc[p][q], 0, 0, 0);
        #pragma unroll
        for (int p = 0; p < 4; ++p)
            #pragma unroll
            for (int q = 0; q < 4; ++q)
                acc[p][q] = __builtin_amdgcn_mfma_f32_16x16x32_bf16(bl[q], ah[p], acc[p][q], 0, 0, 0);
        #pragma unroll
        for (int p = 0; p < 4; ++p)
            #pragma unroll
            for (int q = 0; q < 4; ++q)
                acc[p][q] = __builtin_amdgcn_mfma_f32_16x16x32_bf16(bh[q], al[p], acc[p][q], 0, 0, 0);
    }

    // ---- epilogue: D^T layout => lane holds row (i0+wr+p*16+fr), cols (wc+q*16+kg*4 .. +3)
    #pragma unroll
    for (int p = 0; p < 4; ++p) {
        int ri = wr + p * 16 + fr;
        float sa = sq[i0 + ri];
        float* rowp = out + (size_t)(i0 + ri) * N + j0;
        #pragma unroll
        for (int q = 0; q < 4; ++q) {
            int c = wc + q * 16 + kg * 4;
            float4 sb = *(const float4*)&sq[j0 + c];
            f32x4 a = acc[p][q];
            float4 r;
            r.x = __expf(-GAMMA * fmaxf(fmaf(-2.f, a[0], sa + sb.x), 0.f));
            r.y = __expf(-GAMMA * fmaxf(fmaf(-2.f, a[1], sa + sb.y), 0.f));
            r.z = __expf(-GAMMA * fmaxf(fmaf(-2.f, a[2], sa + sb.z), 0.f));
            r.w = __expf(-GAMMA * fmaxf(fmaf(-2.f, a[3], sa + sb.w), 0.f));
            *(float4*)(rowp + c) = r;
        }
    }
}

extern "C" void kernel_launch(void* const* d_in, const int* in_sizes, int n_in,
                              void* d_out, int out_size, void* d_ws, size_t ws_size,
                              hipStream_t stream) {
    (void)n_in; (void)ws_size; (void)out_size;
    const float* x = (const float*)d_in[0];
    float* out = (float*)d_out;
    const int K = 64;
    const int N = in_sizes[0] / K;   // 8192

    unsigned short* Xh = (unsigned short*)d_ws;              // N*64 bf16 = 1 MB
    unsigned short* Xl = Xh + (size_t)N * K;                 // 1 MB
    float* sq = (float*)(Xl + (size_t)N * K);                // 32 KB

    split_kernel<<<dim3(N * K / 4 / 256), dim3(256), 0, stream>>>(x, Xh, Xl, sq);
    rbf_mfma2<<<dim3(N / 128, N / 128), dim3(256), 0, stream>>>(Xh, Xl, sq, out, N);
}